// Round 1
// baseline (622.755 us; speedup 1.0000x reference)
//
#include <hip/hip_runtime.h>
#include <hip/hip_bf16.h>
#include <math.h>

// ---------------------------------------------------------------------------
// BarrierNet forward, fp32 correctness baseline.
// Pipeline:
//   L1: x(8192x5) @ W1(5x1024) + b1, relu            -> x1   (custom kernel, K=5)
//   L2: x1 @ W2(1024x1024) + b2, relu                -> x2   (tiled SGEMM)
//   L31/L32: x2 @ W3*(1024x512) + b3*, relu          -> x31,x32
//   L41/L42: x3* @ W4*(512x512) + b4*, relu          -> x41,x42
//   head: x41@W51+b51, 4*sigmoid(x42@W52+b52), CBF/QP epilogue -> out(8192x2)
// ---------------------------------------------------------------------------

#define BM 64
#define BN 64
#define BK 16

__global__ __launch_bounds__(256) void gemm_bias_relu(
    const float* __restrict__ A, const float* __restrict__ W,
    const float* __restrict__ bias, float* __restrict__ C,
    int M, int N, int K, int do_relu)
{
    __shared__ float sA[BK][BM];   // A tile, transposed (k-major)
    __shared__ float sB[BK][BN];

    const int tid = threadIdx.x;
    const int n0 = blockIdx.x * BN;
    const int m0 = blockIdx.y * BM;

    const int tx = tid & 15;       // 16 cols of threads
    const int ty = tid >> 4;       // 16 rows of threads

    // load-phase indices
    const int a_m  = tid >> 2;        // 0..63
    const int a_k4 = (tid & 3) * 4;   // 0,4,8,12
    const int b_k  = tid >> 4;        // 0..15
    const int b_n4 = (tid & 15) * 4;  // 0..60

    float acc[4][4] = {};

    for (int k0 = 0; k0 < K; k0 += BK) {
        float4 av = *reinterpret_cast<const float4*>(
            &A[(size_t)(m0 + a_m) * K + k0 + a_k4]);
        sA[a_k4 + 0][a_m] = av.x;
        sA[a_k4 + 1][a_m] = av.y;
        sA[a_k4 + 2][a_m] = av.z;
        sA[a_k4 + 3][a_m] = av.w;
        *reinterpret_cast<float4*>(&sB[b_k][b_n4]) =
            *reinterpret_cast<const float4*>(&W[(size_t)(k0 + b_k) * N + n0 + b_n4]);
        __syncthreads();

        #pragma unroll
        for (int kk = 0; kk < BK; ++kk) {
            float a[4], b[4];
            #pragma unroll
            for (int i = 0; i < 4; ++i) a[i] = sA[kk][ty * 4 + i];
            #pragma unroll
            for (int j = 0; j < 4; ++j) b[j] = sB[kk][tx * 4 + j];
            #pragma unroll
            for (int i = 0; i < 4; ++i)
                #pragma unroll
                for (int j = 0; j < 4; ++j)
                    acc[i][j] += a[i] * b[j];
        }
        __syncthreads();
    }

    #pragma unroll
    for (int i = 0; i < 4; ++i) {
        const int m = m0 + ty * 4 + i;
        #pragma unroll
        for (int j = 0; j < 4; ++j) {
            const int n = n0 + tx * 4 + j;
            float v = acc[i][j] + bias[n];
            if (do_relu) v = fmaxf(v, 0.0f);
            C[(size_t)m * N + n] = v;
        }
    }
}

// Layer 1: K=5, N=1024. One block per row, each thread does one float4 of cols.
__global__ __launch_bounds__(256) void layer1_kernel(
    const float* __restrict__ x, const float* __restrict__ W1,
    const float* __restrict__ b1, float* __restrict__ x1out)
{
    const int row = blockIdx.x;
    const int j4 = threadIdx.x * 4;
    float xr[5];
    #pragma unroll
    for (int k = 0; k < 5; ++k) xr[k] = x[row * 5 + k];
    float4 acc = *reinterpret_cast<const float4*>(&b1[j4]);
    #pragma unroll
    for (int k = 0; k < 5; ++k) {
        float4 w = *reinterpret_cast<const float4*>(&W1[k * 1024 + j4]);
        acc.x = fmaf(xr[k], w.x, acc.x);
        acc.y = fmaf(xr[k], w.y, acc.y);
        acc.z = fmaf(xr[k], w.z, acc.z);
        acc.w = fmaf(xr[k], w.w, acc.w);
    }
    acc.x = fmaxf(acc.x, 0.f);
    acc.y = fmaxf(acc.y, 0.f);
    acc.z = fmaxf(acc.z, 0.f);
    acc.w = fmaxf(acc.w, 0.f);
    *reinterpret_cast<float4*>(&x1out[(size_t)row * 1024 + j4]) = acc;
}

// Heads + barrier-function epilogue. One wave (64 lanes) per batch row.
__global__ __launch_bounds__(256) void head_kernel(
    const float* __restrict__ x41, const float* __restrict__ x42,
    const float* __restrict__ W51, const float* __restrict__ b51,
    const float* __restrict__ W52, const float* __restrict__ b52,
    const float* __restrict__ x,   const float* __restrict__ mean,
    const float* __restrict__ stdv, const float* __restrict__ mean_label,
    const float* __restrict__ std_label, float* __restrict__ out)
{
    const int wave = threadIdx.x >> 6;
    const int lane = threadIdx.x & 63;
    const int row = blockIdx.x * 4 + wave;

    const float* p41 = x41 + (size_t)row * 512;
    const float* p42 = x42 + (size_t)row * 512;

    float a0 = 0.f, a1 = 0.f, a2 = 0.f, a3 = 0.f;
    #pragma unroll
    for (int it = 0; it < 8; ++it) {
        const int k = lane + it * 64;
        const float v1 = p41[k];
        const float2 w5 = *reinterpret_cast<const float2*>(&W51[k * 2]);
        a0 = fmaf(v1, w5.x, a0);
        a1 = fmaf(v1, w5.y, a1);
        const float v2 = p42[k];
        const float2 w6 = *reinterpret_cast<const float2*>(&W52[k * 2]);
        a2 = fmaf(v2, w6.x, a2);
        a3 = fmaf(v2, w6.y, a3);
    }
    #pragma unroll
    for (int off = 32; off >= 1; off >>= 1) {
        a0 += __shfl_down(a0, off);
        a1 += __shfl_down(a1, off);
        a2 += __shfl_down(a2, off);
        a3 += __shfl_down(a3, off);
    }

    if (lane == 0) {
        const float L1c = 3.0f, L2c = 3.0f, OBSX = 0.0f, OBSY = 7.0f, Rc = 4.0f;
        const float t1 = x[row * 5 + 0] * stdv[0] + mean[0];
        const float w1 = x[row * 5 + 1] * stdv[1] + mean[1];
        const float t2 = x[row * 5 + 2] * stdv[2] + mean[2];
        const float w2 = x[row * 5 + 3] * stdv[3] + mean[3];
        const float s1 = sinf(t1), c1 = cosf(t1);
        const float s2 = sinf(t2), c2 = cosf(t2);
        const float px = L1c * c1 + L2c * c2 - OBSX;
        const float py = L1c * s1 + L2c * s2 - OBSY;
        const float vx = -L1c * s1 * w1 - L2c * s2 * w2;
        const float vy =  L1c * c1 * w1 + L2c * c2 * w2;
        const float barrier = px * px + py * py - Rc * Rc;
        const float b_dot = 2.0f * (px * vx + py * vy);
        const float Lf2b = 2.0f * (vx * vx + vy * vy)
                         + 2.0f * px * (-L1c * c1 * w1 * w1 - L2c * c2 * w2 * w2)
                         + 2.0f * py * (-L1c * s1 * w1 * w1 - L2c * s2 * w2 * w2);
        const float G1 = -(2.0f * px * (-L1c * s1) + 2.0f * py * (L1c * c1));
        const float G2 = -(2.0f * px * (-L2c * s2) + 2.0f * py * (L2c * c2));

        const float x51_0 = a0 + b51[0];
        const float x51_1 = a1 + b51[1];
        const float z0 = a2 + b52[0];
        const float z1 = a3 + b52[1];
        const float x52_0 = 4.0f / (1.0f + expf(-z0));
        const float x52_1 = 4.0f / (1.0f + expf(-z1));

        const float u0_0 = -x51_0;
        const float u0_1 = -x51_1;
        const float h = Lf2b + (x52_0 + x52_1) * b_dot + x52_0 * x52_1 * barrier;
        const float viol = G1 * u0_0 + G2 * u0_1 - h;
        const float lam = fmaxf(viol, 0.0f) / (G1 * G1 + G2 * G2 + 1e-12f);
        const float u_0 = u0_0 - lam * G1;
        const float u_1 = u0_1 - lam * G2;
        out[row * 2 + 0] = (u_0 - mean_label[0]) / std_label[0];
        out[row * 2 + 1] = (u_1 - mean_label[1]) / std_label[1];
    }
}

extern "C" void kernel_launch(void* const* d_in, const int* in_sizes, int n_in,
                              void* d_out, int out_size, void* d_ws, size_t ws_size,
                              hipStream_t stream) {
    const float* x          = (const float*)d_in[0];
    // d_in[1] = sgn (unused)
    const float* mean       = (const float*)d_in[2];
    const float* stdv       = (const float*)d_in[3];
    const float* mean_label = (const float*)d_in[4];
    const float* std_label  = (const float*)d_in[5];
    const float* W1  = (const float*)d_in[6];   const float* b1  = (const float*)d_in[7];
    const float* W2  = (const float*)d_in[8];   const float* b2  = (const float*)d_in[9];
    const float* W31 = (const float*)d_in[10];  const float* b31 = (const float*)d_in[11];
    const float* W32 = (const float*)d_in[12];  const float* b32 = (const float*)d_in[13];
    const float* W41 = (const float*)d_in[14];  const float* b41 = (const float*)d_in[15];
    const float* W42 = (const float*)d_in[16];  const float* b42 = (const float*)d_in[17];
    const float* W51 = (const float*)d_in[18];  const float* b51 = (const float*)d_in[19];
    const float* W52 = (const float*)d_in[20];  const float* b52 = (const float*)d_in[21];
    float* out = (float*)d_out;

    char* ws = (char*)d_ws;
    // buffer plan (64 MiB total, with reuse):
    //   [0,       33.5MB) : x1, later x31(16.7MB)+x32(16.7MB)
    //   [33.5MB,  67MB)   : x2, later x41(16.7MB)+x42(16.7MB)
    float* x1  = (float*)(ws + 0);
    float* x2  = (float*)(ws + (size_t)33554432);
    float* x31 = (float*)(ws + 0);
    float* x32 = (float*)(ws + (size_t)16777216);
    float* x41 = (float*)(ws + (size_t)33554432);
    float* x42 = (float*)(ws + (size_t)50331648);

    layer1_kernel<<<8192, 256, 0, stream>>>(x, W1, b1, x1);

    dim3 g2(1024 / BN, 8192 / BM);
    gemm_bias_relu<<<g2, 256, 0, stream>>>(x1, W2, b2, x2, 8192, 1024, 1024, 1);

    dim3 g3(512 / BN, 8192 / BM);
    gemm_bias_relu<<<g3, 256, 0, stream>>>(x2,  W31, b31, x31, 8192, 512, 1024, 1);
    gemm_bias_relu<<<g3, 256, 0, stream>>>(x2,  W32, b32, x32, 8192, 512, 1024, 1);
    gemm_bias_relu<<<g3, 256, 0, stream>>>(x31, W41, b41, x41, 8192, 512, 512, 1);
    gemm_bias_relu<<<g3, 256, 0, stream>>>(x32, W42, b42, x42, 8192, 512, 512, 1);

    head_kernel<<<2048, 256, 0, stream>>>(x41, x42, W51, b51, W52, b52,
                                          x, mean, stdv, mean_label, std_label, out);
}

// Round 2
// 130.531 us; speedup vs baseline: 4.7709x; 4.7709x over previous
//
#include <hip/hip_runtime.h>
#include <hip/hip_bf16.h>
#include <math.h>

// ---------------------------------------------------------------------------
// BarrierNet forward, bf16-MFMA pipeline (m97-structure GEMM).
//   prep : transpose+convert weights fp32(K,N) -> bf16(N,K); concat b3
//   L1   : x(8192x5)@W1+b1, relu (fp32 math)            -> xb1  bf16
//   L2   : xb1 @ W2t + b2, relu  (MFMA)                 -> x2b  bf16
//   L3   : x2b @ [W31|W32]t + b3cat, relu (MFMA, N=1024)-> x3   bf16 (x31|x32)
//   L41/42: x3 slices @ W4*t + b4*, relu (MFMA)         -> x4   bf16 (x41|x42)
//   head : fp32 dot with W51/W52 + exact CBF/QP epilogue -> out fp32
// ---------------------------------------------------------------------------

typedef __attribute__((ext_vector_type(4))) float f32x4;
typedef __attribute__((ext_vector_type(8))) short bf16x8;

static __device__ __forceinline__ unsigned short f2bf(float f) {
    unsigned int u = __float_as_uint(f);
    unsigned int r = (u + 0x7fffu + ((u >> 16) & 1u)) >> 16;
    return (unsigned short)r;
}
static __device__ __forceinline__ float bf2f(unsigned short h) {
    return __uint_as_float(((unsigned int)h) << 16);
}

#define TM 128
#define TN 128
#define TK 32

#define GLL(gp, lp) __builtin_amdgcn_global_load_lds( \
    (const __attribute__((address_space(1))) void*)(gp), \
    (__attribute__((address_space(3))) void*)(lp), 16, 0, 0)

// C = relu(A @ Bt^T + bias). A: MxK bf16 row-major (lda), Bt: NxK bf16
// row-major (ldb), C: bf16 (ldc). K % 32 == 0. Tiles 128x128.
__global__ __launch_bounds__(256) void gemm_bf16(
    const unsigned short* __restrict__ A, int lda,
    const unsigned short* __restrict__ Bt, int ldb,
    const float* __restrict__ bias,
    unsigned short* __restrict__ C, int ldc,
    int K, int do_relu)
{
    __shared__ __align__(16) short sA[TM * TK];   // [128][32]
    __shared__ __align__(16) short sB[TN * TK];

    const int tid  = threadIdx.x;
    const int w    = tid >> 6;        // wave 0..3
    const int lane = tid & 63;
    const int m0 = blockIdx.y * TM;
    const int n0 = blockIdx.x * TN;

    // staging: per wave, 2 calls for A (16 rows each) + 2 for B.
    // row covered by a call: w*32 + c*16 + lane/4 ; 8 bf16 at col (lane&3)*8
    const unsigned short* aG =
        A + (size_t)(m0 + w * 32 + (lane >> 2)) * lda + (lane & 3) * 8;
    const unsigned short* bG =
        Bt + (size_t)(n0 + w * 32 + (lane >> 2)) * ldb + (lane & 3) * 8;
    short* ldsA = sA + w * 1024;      // wave-uniform; HW adds lane*16 bytes
    short* ldsB = sB + w * 1024;

    const int wr = (w >> 1) * 64;     // wave sub-tile origin in tile coords
    const int wc = (w & 1) * 64;
    const int fr = lane & 15;         // fragment row/col
    const int fq = lane >> 4;         // 0..3

    f32x4 acc[4][4] = {};

    for (int k0 = 0; k0 < K; k0 += TK) {
        GLL(aG,            ldsA);
        GLL(aG + 16 * lda, ldsA + 512);
        GLL(bG,            ldsB);
        GLL(bG + 16 * ldb, ldsB + 512);
        aG += TK; bG += TK;
        __syncthreads();

        bf16x8 af[4], bfr[4];
        #pragma unroll
        for (int m = 0; m < 4; ++m)
            af[m] = *reinterpret_cast<const bf16x8*>(
                &sA[(wr + m * 16 + fr) * TK + fq * 8]);
        #pragma unroll
        for (int n = 0; n < 4; ++n)
            bfr[n] = *reinterpret_cast<const bf16x8*>(
                &sB[(wc + n * 16 + fr) * TK + fq * 8]);
        #pragma unroll
        for (int m = 0; m < 4; ++m)
            #pragma unroll
            for (int n = 0; n < 4; ++n)
                acc[m][n] = __builtin_amdgcn_mfma_f32_16x16x32_bf16(
                    af[m], bfr[n], acc[m][n], 0, 0, 0);
        __syncthreads();
    }

    // C/D layout: col = lane&15, row = (lane>>4)*4 + reg   [m89/m91 verified]
    #pragma unroll
    for (int n = 0; n < 4; ++n) {
        const int col = n0 + wc + n * 16 + fr;
        const float bv = bias[col];
        #pragma unroll
        for (int m = 0; m < 4; ++m) {
            const int rbase = m0 + wr + m * 16 + fq * 4;
            #pragma unroll
            for (int r = 0; r < 4; ++r) {
                float v = acc[m][n][r] + bv;
                if (do_relu) v = fmaxf(v, 0.0f);
                C[(size_t)(rbase + r) * ldc + col] = f2bf(v);
            }
        }
    }
}

// fp32 (K,N) -> bf16 (N,K) transpose. K,N % 32 == 0. Wt row stride = K.
__global__ __launch_bounds__(256) void transpose_to_bf16(
    const float* __restrict__ W, unsigned short* __restrict__ Wt, int K, int N)
{
    __shared__ float t[32][33];
    const int k0 = blockIdx.x * 32, n0 = blockIdx.y * 32;
    const int tx = threadIdx.x & 31, ty = threadIdx.x >> 5; // 32 x 8
    #pragma unroll
    for (int i = 0; i < 32; i += 8)
        t[ty + i][tx] = W[(size_t)(k0 + ty + i) * N + n0 + tx];
    __syncthreads();
    #pragma unroll
    for (int i = 0; i < 32; i += 8)
        Wt[(size_t)(n0 + ty + i) * K + k0 + tx] = f2bf(t[tx][ty + i]);
}

__global__ void concat_bias(const float* __restrict__ b31,
                            const float* __restrict__ b32,
                            float* __restrict__ b3cat)
{
    const int i = blockIdx.x * 256 + threadIdx.x;
    if (i < 1024) b3cat[i] = (i < 512) ? b31[i] : b32[i - 512];
}

// Layer 1: K=5, N=1024, fp32 math, bf16 out.
__global__ __launch_bounds__(256) void layer1_kernel(
    const float* __restrict__ x, const float* __restrict__ W1,
    const float* __restrict__ b1, unsigned short* __restrict__ x1out)
{
    const int row = blockIdx.x;
    const int j4 = threadIdx.x * 4;
    float xr[5];
    #pragma unroll
    for (int k = 0; k < 5; ++k) xr[k] = x[row * 5 + k];
    float4 acc = *reinterpret_cast<const float4*>(&b1[j4]);
    #pragma unroll
    for (int k = 0; k < 5; ++k) {
        float4 w = *reinterpret_cast<const float4*>(&W1[k * 1024 + j4]);
        acc.x = fmaf(xr[k], w.x, acc.x);
        acc.y = fmaf(xr[k], w.y, acc.y);
        acc.z = fmaf(xr[k], w.z, acc.z);
        acc.w = fmaf(xr[k], w.w, acc.w);
    }
    ushort4 o;
    o.x = f2bf(fmaxf(acc.x, 0.f));
    o.y = f2bf(fmaxf(acc.y, 0.f));
    o.z = f2bf(fmaxf(acc.z, 0.f));
    o.w = f2bf(fmaxf(acc.w, 0.f));
    *reinterpret_cast<ushort4*>(&x1out[(size_t)row * 1024 + j4]) = o;
}

// Heads + exact CBF/QP epilogue. One wave per batch row. x4 = [x41|x42], ld 1024.
__global__ __launch_bounds__(256) void head_kernel(
    const unsigned short* __restrict__ x4,
    const float* __restrict__ W51, const float* __restrict__ b51,
    const float* __restrict__ W52, const float* __restrict__ b52,
    const float* __restrict__ x,   const float* __restrict__ mean,
    const float* __restrict__ stdv, const float* __restrict__ mean_label,
    const float* __restrict__ std_label, float* __restrict__ out)
{
    const int wave = threadIdx.x >> 6;
    const int lane = threadIdx.x & 63;
    const int row = blockIdx.x * 4 + wave;

    const unsigned short* p41 = x4 + (size_t)row * 1024;
    const unsigned short* p42 = p41 + 512;

    float a0 = 0.f, a1 = 0.f, a2 = 0.f, a3 = 0.f;
    #pragma unroll
    for (int it = 0; it < 8; ++it) {
        const int k = lane + it * 64;
        const float v1 = bf2f(p41[k]);
        const float2 w5 = *reinterpret_cast<const float2*>(&W51[k * 2]);
        a0 = fmaf(v1, w5.x, a0);
        a1 = fmaf(v1, w5.y, a1);
        const float v2 = bf2f(p42[k]);
        const float2 w6 = *reinterpret_cast<const float2*>(&W52[k * 2]);
        a2 = fmaf(v2, w6.x, a2);
        a3 = fmaf(v2, w6.y, a3);
    }
    #pragma unroll
    for (int off = 32; off >= 1; off >>= 1) {
        a0 += __shfl_down(a0, off);
        a1 += __shfl_down(a1, off);
        a2 += __shfl_down(a2, off);
        a3 += __shfl_down(a3, off);
    }

    if (lane == 0) {
        const float L1c = 3.0f, L2c = 3.0f, OBSX = 0.0f, OBSY = 7.0f, Rc = 4.0f;
        const float t1 = x[row * 5 + 0] * stdv[0] + mean[0];
        const float w1 = x[row * 5 + 1] * stdv[1] + mean[1];
        const float t2 = x[row * 5 + 2] * stdv[2] + mean[2];
        const float w2 = x[row * 5 + 3] * stdv[3] + mean[3];
        const float s1 = sinf(t1), c1 = cosf(t1);
        const float s2 = sinf(t2), c2 = cosf(t2);
        const float px = L1c * c1 + L2c * c2 - OBSX;
        const float py = L1c * s1 + L2c * s2 - OBSY;
        const float vx = -L1c * s1 * w1 - L2c * s2 * w2;
        const float vy =  L1c * c1 * w1 + L2c * c2 * w2;
        const float barrier = px * px + py * py - Rc * Rc;
        const float b_dot = 2.0f * (px * vx + py * vy);
        const float Lf2b = 2.0f * (vx * vx + vy * vy)
                         + 2.0f * px * (-L1c * c1 * w1 * w1 - L2c * c2 * w2 * w2)
                         + 2.0f * py * (-L1c * s1 * w1 * w1 - L2c * s2 * w2 * w2);
        const float G1 = -(2.0f * px * (-L1c * s1) + 2.0f * py * (L1c * c1));
        const float G2 = -(2.0f * px * (-L2c * s2) + 2.0f * py * (L2c * c2));

        const float x51_0 = a0 + b51[0];
        const float x51_1 = a1 + b51[1];
        const float z0 = a2 + b52[0];
        const float z1 = a3 + b52[1];
        const float x52_0 = 4.0f / (1.0f + expf(-z0));
        const float x52_1 = 4.0f / (1.0f + expf(-z1));

        const float u0_0 = -x51_0;
        const float u0_1 = -x51_1;
        const float h = Lf2b + (x52_0 + x52_1) * b_dot + x52_0 * x52_1 * barrier;
        const float viol = G1 * u0_0 + G2 * u0_1 - h;
        const float lam = fmaxf(viol, 0.0f) / (G1 * G1 + G2 * G2 + 1e-12f);
        const float u_0 = u0_0 - lam * G1;
        const float u_1 = u0_1 - lam * G2;
        out[row * 2 + 0] = (u_0 - mean_label[0]) / std_label[0];
        out[row * 2 + 1] = (u_1 - mean_label[1]) / std_label[1];
    }
}

extern "C" void kernel_launch(void* const* d_in, const int* in_sizes, int n_in,
                              void* d_out, int out_size, void* d_ws, size_t ws_size,
                              hipStream_t stream) {
    const float* x          = (const float*)d_in[0];
    const float* mean       = (const float*)d_in[2];
    const float* stdv       = (const float*)d_in[3];
    const float* mean_label = (const float*)d_in[4];
    const float* std_label  = (const float*)d_in[5];
    const float* W1  = (const float*)d_in[6];   const float* b1  = (const float*)d_in[7];
    const float* W2  = (const float*)d_in[8];   const float* b2  = (const float*)d_in[9];
    const float* W31 = (const float*)d_in[10];  const float* b31 = (const float*)d_in[11];
    const float* W32 = (const float*)d_in[12];  const float* b32 = (const float*)d_in[13];
    const float* W41 = (const float*)d_in[14];  const float* b41 = (const float*)d_in[15];
    const float* W42 = (const float*)d_in[16];  const float* b42 = (const float*)d_in[17];
    const float* W51 = (const float*)d_in[18];  const float* b51 = (const float*)d_in[19];
    const float* W52 = (const float*)d_in[20];  const float* b52 = (const float*)d_in[21];
    float* out = (float*)d_out;

    char* ws = (char*)d_ws;
    const size_t MiB = 1024 * 1024;
    // [0,16Mi):    act0 = xb1, later x3 ([x31|x32], ld 1024)
    // [16,32Mi):   act1 = x2b, later x4 ([x41|x42], ld 1024)
    // [32,34Mi):   W2t (1024x1024 bf16)
    // [34,36Mi):   W3t ([W31|W32]^T, 1024 rows x 1024 k)
    // [36,36.5Mi): W41t ; [36.5,37Mi): W42t ; [37Mi,+4KB): b3cat
    unsigned short* xb1  = (unsigned short*)(ws + 0);
    unsigned short* x2b  = (unsigned short*)(ws + 16 * MiB);
    unsigned short* x3   = xb1;
    unsigned short* x4   = x2b;
    unsigned short* W2t  = (unsigned short*)(ws + 32 * MiB);
    unsigned short* W3t  = (unsigned short*)(ws + 34 * MiB);
    unsigned short* W41t = (unsigned short*)(ws + 36 * MiB);
    unsigned short* W42t = (unsigned short*)(ws + 36 * MiB + 512 * 1024);
    float*          b3c  = (float*)(ws + 37 * MiB);

    // weight prep (independent of activations)
    transpose_to_bf16<<<dim3(32, 32), 256, 0, stream>>>(W2, W2t, 1024, 1024);
    transpose_to_bf16<<<dim3(32, 16), 256, 0, stream>>>(W31, W3t, 1024, 512);
    transpose_to_bf16<<<dim3(32, 16), 256, 0, stream>>>(W32, W3t + 512 * 1024, 1024, 512);
    transpose_to_bf16<<<dim3(16, 16), 256, 0, stream>>>(W41, W41t, 512, 512);
    transpose_to_bf16<<<dim3(16, 16), 256, 0, stream>>>(W42, W42t, 512, 512);
    concat_bias<<<4, 256, 0, stream>>>(b31, b32, b3c);

    layer1_kernel<<<8192, 256, 0, stream>>>(x, W1, b1, xb1);

    dim3 gL2(1024 / TN, 8192 / TM);
    gemm_bf16<<<gL2, 256, 0, stream>>>(xb1, 1024, W2t, 1024, b2, x2b, 1024, 1024, 1);
    gemm_bf16<<<gL2, 256, 0, stream>>>(x2b, 1024, W3t, 1024, b3c, x3, 1024, 1024, 1);

    dim3 gL4(512 / TN, 8192 / TM);
    gemm_bf16<<<gL4, 256, 0, stream>>>(x3,       1024, W41t, 512, b41, x4,       1024, 512, 1);
    gemm_bf16<<<gL4, 256, 0, stream>>>(x3 + 512, 1024, W42t, 512, b42, x4 + 512, 1024, 512, 1);

    head_kernel<<<2048, 256, 0, stream>>>(x4, W51, b51, W52, b52,
                                          x, mean, stdv, mean_label, std_label, out);
}

// Round 3
// 98.439 us; speedup vs baseline: 6.3263x; 1.3260x over previous
//
#include <hip/hip_runtime.h>
#include <hip/hip_bf16.h>
#include <math.h>

// ---------------------------------------------------------------------------
// BarrierNet forward, bf16-MFMA pipeline, round 3.
//   prep  : ONE kernel — all weight transposes fp32(K,N)->bf16(N,K) + b3 concat
//   L1    : x(8192x5)@W1+b1, relu (fp32 math)              -> xb1 bf16
//   L2    : xb1 @ W2t^T + b2, relu   (MFMA, dbuf+vmcnt(4)) -> x2b
//   L3    : x2b @ [W31|W32]t^T + b3c, relu                 -> x3 ([x31|x32])
//   L4    : grouped GEMM: x3[:,g*512:] @ W4g^T + b4g, relu -> x4 ([x41|x42])
//   head  : fp32 dots with W51/W52 + exact CBF/QP epilogue -> out
// GEMM inner loop: double-buffered LDS, counted s_waitcnt vmcnt(4) so staging
// loads stay in flight across barriers (T4); 2 barriers / K-step, no drain.
// ---------------------------------------------------------------------------

typedef __attribute__((ext_vector_type(4))) float f32x4;
typedef __attribute__((ext_vector_type(8))) short bf16x8;

static __device__ __forceinline__ unsigned short f2bf(float f) {
    unsigned int u = __float_as_uint(f);
    unsigned int r = (u + 0x7fffu + ((u >> 16) & 1u)) >> 16;
    return (unsigned short)r;
}
static __device__ __forceinline__ float bf2f(unsigned short h) {
    return __uint_as_float(((unsigned int)h) << 16);
}

#define TM 128
#define TN 128
#define TK 32

#define GLL(gp, lp) __builtin_amdgcn_global_load_lds( \
    (const __attribute__((address_space(1))) void*)(gp), \
    (__attribute__((address_space(3))) void*)(lp), 16, 0, 0)

#define LGKM0() asm volatile("s_waitcnt lgkmcnt(0)" ::: "memory")
#define VMC(N)  asm volatile("s_waitcnt vmcnt(" #N ")" ::: "memory")
#define BAR()   __builtin_amdgcn_s_barrier()
#define SB0()   __builtin_amdgcn_sched_barrier(0)

// Core 128x128 tile GEMM: C[., c0+j] = relu(A[m0+i,:] . Bt[n0b+j,:] + bias[n0b+j])
// A: bf16 row-major lda; Bt: bf16 row-major ldb (N x K); K % 64 == 0 (nt even).
__device__ __forceinline__ void gemm_core(
    const unsigned short* __restrict__ A, int lda,
    const unsigned short* __restrict__ Bt, int ldb,
    const float* __restrict__ bias,
    unsigned short* __restrict__ C, int ldc,
    int K, int m0, int n0b, int c0)
{
    __shared__ __align__(16) short sA0[TM * TK], sB0v[TN * TK];
    __shared__ __align__(16) short sA1[TM * TK], sB1v[TN * TK];

    const int tid  = threadIdx.x;
    const int w    = tid >> 6;
    const int lane = tid & 63;

    const unsigned short* aG =
        A + (size_t)(m0 + w * 32 + (lane >> 2)) * lda + (lane & 3) * 8;
    const unsigned short* bG =
        Bt + (size_t)(n0b + w * 32 + (lane >> 2)) * ldb + (lane & 3) * 8;

    const int wr = (w >> 1) * 64;
    const int wc = (w & 1) * 64;
    const int fr = lane & 15;
    const int fq = lane >> 4;

    f32x4 acc[4][4] = {};
    const int nt = K / TK;            // 16 or 32, always even

    auto STAGE = [&](int kt, short* la, short* lb) {
        const unsigned short* a0 = aG + (size_t)kt * TK;
        const unsigned short* b0 = bG + (size_t)kt * TK;
        GLL(a0,            la + w * 1024);
        GLL(a0 + 16 * lda, la + w * 1024 + 512);
        GLL(b0,            lb + w * 1024);
        GLL(b0 + 16 * ldb, lb + w * 1024 + 512);
    };

    auto BODY = [&](int t, short* sAp, short* sBp) {
        bf16x8 af[4], bf[4];
        #pragma unroll
        for (int m = 0; m < 4; ++m)
            af[m] = *reinterpret_cast<const bf16x8*>(
                &sAp[(wr + m * 16 + fr) * TK + fq * 8]);
        #pragma unroll
        for (int n = 0; n < 4; ++n)
            bf[n] = *reinterpret_cast<const bf16x8*>(
                &sBp[(wc + n * 16 + fr) * TK + fq * 8]);
        LGKM0();                       // my reads of this buffer are done
        BAR();                         // ...everyone's are
        SB0();
        if (t + 2 < nt) STAGE(t + 2, sAp, sBp);   // overwrite freed buffer
        #pragma unroll
        for (int m = 0; m < 4; ++m)
            #pragma unroll
            for (int n = 0; n < 4; ++n)
                acc[m][n] = __builtin_amdgcn_mfma_f32_16x16x32_bf16(
                    af[m], bf[n], acc[m][n], 0, 0, 0);
        if (t + 1 < nt) {
            if (t + 2 < nt) { VMC(4); } else { VMC(0); }  // tile t+1 landed
            BAR();
            SB0();
        }
    };

    STAGE(0, sA0, sB0v);
    STAGE(1, sA1, sB1v);
    VMC(4);                            // tile 0's 4 loads done; tile 1 in flight
    BAR();
    SB0();

    for (int t = 0; t < nt; t += 2) {
        BODY(t,     sA0, sB0v);
        BODY(t + 1, sA1, sB1v);
    }

    // C/D layout: col = lane&15, row = (lane>>4)*4 + reg  [m89/m91 verified]
    #pragma unroll
    for (int n = 0; n < 4; ++n) {
        const int cl = wc + n * 16 + fr;
        const float bv = bias[n0b + cl];
        #pragma unroll
        for (int m = 0; m < 4; ++m) {
            const int rbase = m0 + wr + m * 16 + fq * 4;
            #pragma unroll
            for (int r = 0; r < 4; ++r) {
                float v = fmaxf(acc[m][n][r] + bv, 0.0f);
                C[(size_t)(rbase + r) * ldc + c0 + cl] = f2bf(v);
            }
        }
    }
}

__global__ __launch_bounds__(256) void gemm_bf16(
    const unsigned short* __restrict__ A, int lda,
    const unsigned short* __restrict__ Bt, int ldb,
    const float* __restrict__ bias,
    unsigned short* __restrict__ C, int ldc, int K)
{
    const int n0 = blockIdx.x * TN;
    const int m0 = blockIdx.y * TM;
    gemm_core(A, lda, Bt, ldb, bias, C, ldc, K, m0, n0, n0);
}

// Grouped L4: group g = blockIdx.x>=4. x4[:,g*512+j] = relu(x3[:,g*512:] @ W4g^T + b4g)
__global__ __launch_bounds__(256) void gemm_bf16_l4(
    const unsigned short* __restrict__ x3,
    const unsigned short* __restrict__ W41t,
    const unsigned short* __restrict__ W42t,
    const float* __restrict__ b41, const float* __restrict__ b42,
    unsigned short* __restrict__ x4)
{
    const int g   = blockIdx.x >> 2;
    const int n0b = (blockIdx.x & 3) * TN;
    const int m0  = blockIdx.y * TM;
    const unsigned short* A  = x3 + (g ? 512 : 0);
    const unsigned short* Bt = g ? W42t : W41t;
    const float* bias        = g ? b42 : b41;
    gemm_core(A, 1024, Bt, 512, bias, x4, 1024, 512, m0, n0b, g * 512 + n0b);
}

// All weight prep in one kernel. z: 0=W2, 1=W31, 2=W32, 3=W41, 4=W42, 5=b3cat.
__global__ __launch_bounds__(256) void prep_weights(
    const float* __restrict__ W2,  const float* __restrict__ W31,
    const float* __restrict__ W32, const float* __restrict__ W41,
    const float* __restrict__ W42, const float* __restrict__ b31,
    const float* __restrict__ b32,
    unsigned short* __restrict__ W2t,  unsigned short* __restrict__ W3t,
    unsigned short* __restrict__ W41t, unsigned short* __restrict__ W42t,
    float* __restrict__ b3c)
{
    const int z = blockIdx.z;
    if (z == 5) {
        if (blockIdx.x == 0 && blockIdx.y == 0) {
            for (int i = threadIdx.x; i < 1024; i += 256)
                b3c[i] = (i < 512) ? b31[i] : b32[i - 512];
        }
        return;
    }
    const float* src; unsigned short* dst; int K, N;
    switch (z) {
        case 0:  src = W2;  dst = W2t;              K = 1024; N = 1024; break;
        case 1:  src = W31; dst = W3t;              K = 1024; N = 512;  break;
        case 2:  src = W32; dst = W3t + 512 * 1024; K = 1024; N = 512;  break;
        case 3:  src = W41; dst = W41t;             K = 512;  N = 512;  break;
        default: src = W42; dst = W42t;             K = 512;  N = 512;  break;
    }
    const int k0 = blockIdx.x * 32, n0 = blockIdx.y * 32;
    if (k0 >= K || n0 >= N) return;

    __shared__ float t[32][33];
    const int tx = threadIdx.x & 31, ty = threadIdx.x >> 5;  // 32 x 8
    #pragma unroll
    for (int i = 0; i < 32; i += 8)
        t[ty + i][tx] = src[(size_t)(k0 + ty + i) * N + n0 + tx];
    __syncthreads();
    #pragma unroll
    for (int i = 0; i < 32; i += 8)
        dst[(size_t)(n0 + ty + i) * K + k0 + tx] = f2bf(t[tx][ty + i]);
}

// Layer 1: K=5, N=1024, fp32 math, bf16 out.
__global__ __launch_bounds__(256) void layer1_kernel(
    const float* __restrict__ x, const float* __restrict__ W1,
    const float* __restrict__ b1, unsigned short* __restrict__ x1out)
{
    const int row = blockIdx.x;
    const int j4 = threadIdx.x * 4;
    float xr[5];
    #pragma unroll
    for (int k = 0; k < 5; ++k) xr[k] = x[row * 5 + k];
    float4 acc = *reinterpret_cast<const float4*>(&b1[j4]);
    #pragma unroll
    for (int k = 0; k < 5; ++k) {
        float4 wv = *reinterpret_cast<const float4*>(&W1[k * 1024 + j4]);
        acc.x = fmaf(xr[k], wv.x, acc.x);
        acc.y = fmaf(xr[k], wv.y, acc.y);
        acc.z = fmaf(xr[k], wv.z, acc.z);
        acc.w = fmaf(xr[k], wv.w, acc.w);
    }
    ushort4 o;
    o.x = f2bf(fmaxf(acc.x, 0.f));
    o.y = f2bf(fmaxf(acc.y, 0.f));
    o.z = f2bf(fmaxf(acc.z, 0.f));
    o.w = f2bf(fmaxf(acc.w, 0.f));
    *reinterpret_cast<ushort4*>(&x1out[(size_t)row * 1024 + j4]) = o;
}

// Heads + exact CBF/QP epilogue. One wave per batch row. x4 = [x41|x42], ld 1024.
__global__ __launch_bounds__(256) void head_kernel(
    const unsigned short* __restrict__ x4,
    const float* __restrict__ W51, const float* __restrict__ b51,
    const float* __restrict__ W52, const float* __restrict__ b52,
    const float* __restrict__ x,   const float* __restrict__ mean,
    const float* __restrict__ stdv, const float* __restrict__ mean_label,
    const float* __restrict__ std_label, float* __restrict__ out)
{
    const int wave = threadIdx.x >> 6;
    const int lane = threadIdx.x & 63;
    const int row = blockIdx.x * 4 + wave;

    const unsigned short* p41 = x4 + (size_t)row * 1024;
    const unsigned short* p42 = p41 + 512;

    float a0 = 0.f, a1 = 0.f, a2 = 0.f, a3 = 0.f;
    #pragma unroll
    for (int it = 0; it < 8; ++it) {
        const int k = lane + it * 64;
        const float v1 = bf2f(p41[k]);
        const float2 w5 = *reinterpret_cast<const float2*>(&W51[k * 2]);
        a0 = fmaf(v1, w5.x, a0);
        a1 = fmaf(v1, w5.y, a1);
        const float v2 = bf2f(p42[k]);
        const float2 w6 = *reinterpret_cast<const float2*>(&W52[k * 2]);
        a2 = fmaf(v2, w6.x, a2);
        a3 = fmaf(v2, w6.y, a3);
    }
    #pragma unroll
    for (int off = 32; off >= 1; off >>= 1) {
        a0 += __shfl_down(a0, off);
        a1 += __shfl_down(a1, off);
        a2 += __shfl_down(a2, off);
        a3 += __shfl_down(a3, off);
    }

    if (lane == 0) {
        const float L1c = 3.0f, L2c = 3.0f, OBSX = 0.0f, OBSY = 7.0f, Rc = 4.0f;
        const float t1 = x[row * 5 + 0] * stdv[0] + mean[0];
        const float w1 = x[row * 5 + 1] * stdv[1] + mean[1];
        const float t2 = x[row * 5 + 2] * stdv[2] + mean[2];
        const float w2 = x[row * 5 + 3] * stdv[3] + mean[3];
        const float s1 = sinf(t1), c1 = cosf(t1);
        const float s2 = sinf(t2), c2 = cosf(t2);
        const float px = L1c * c1 + L2c * c2 - OBSX;
        const float py = L1c * s1 + L2c * s2 - OBSY;
        const float vx = -L1c * s1 * w1 - L2c * s2 * w2;
        const float vy =  L1c * c1 * w1 + L2c * c2 * w2;
        const float barrier = px * px + py * py - Rc * Rc;
        const float b_dot = 2.0f * (px * vx + py * vy);
        const float Lf2b = 2.0f * (vx * vx + vy * vy)
                         + 2.0f * px * (-L1c * c1 * w1 * w1 - L2c * c2 * w2 * w2)
                         + 2.0f * py * (-L1c * s1 * w1 * w1 - L2c * s2 * w2 * w2);
        const float G1 = -(2.0f * px * (-L1c * s1) + 2.0f * py * (L1c * c1));
        const float G2 = -(2.0f * px * (-L2c * s2) + 2.0f * py * (L2c * c2));

        const float x51_0 = a0 + b51[0];
        const float x51_1 = a1 + b51[1];
        const float z0 = a2 + b52[0];
        const float z1 = a3 + b52[1];
        const float x52_0 = 4.0f / (1.0f + expf(-z0));
        const float x52_1 = 4.0f / (1.0f + expf(-z1));

        const float u0_0 = -x51_0;
        const float u0_1 = -x51_1;
        const float h = Lf2b + (x52_0 + x52_1) * b_dot + x52_0 * x52_1 * barrier;
        const float viol = G1 * u0_0 + G2 * u0_1 - h;
        const float lam = fmaxf(viol, 0.0f) / (G1 * G1 + G2 * G2 + 1e-12f);
        const float u_0 = u0_0 - lam * G1;
        const float u_1 = u0_1 - lam * G2;
        out[row * 2 + 0] = (u_0 - mean_label[0]) / std_label[0];
        out[row * 2 + 1] = (u_1 - mean_label[1]) / std_label[1];
    }
}

extern "C" void kernel_launch(void* const* d_in, const int* in_sizes, int n_in,
                              void* d_out, int out_size, void* d_ws, size_t ws_size,
                              hipStream_t stream) {
    const float* x          = (const float*)d_in[0];
    const float* mean       = (const float*)d_in[2];
    const float* stdv       = (const float*)d_in[3];
    const float* mean_label = (const float*)d_in[4];
    const float* std_label  = (const float*)d_in[5];
    const float* W1  = (const float*)d_in[6];   const float* b1  = (const float*)d_in[7];
    const float* W2  = (const float*)d_in[8];   const float* b2  = (const float*)d_in[9];
    const float* W31 = (const float*)d_in[10];  const float* b31 = (const float*)d_in[11];
    const float* W32 = (const float*)d_in[12];  const float* b32 = (const float*)d_in[13];
    const float* W41 = (const float*)d_in[14];  const float* b41 = (const float*)d_in[15];
    const float* W42 = (const float*)d_in[16];  const float* b42 = (const float*)d_in[17];
    const float* W51 = (const float*)d_in[18];  const float* b51 = (const float*)d_in[19];
    const float* W52 = (const float*)d_in[20];  const float* b52 = (const float*)d_in[21];
    float* out = (float*)d_out;

    char* ws = (char*)d_ws;
    const size_t MiB = 1024 * 1024;
    unsigned short* xb1  = (unsigned short*)(ws + 0);         // later x3
    unsigned short* x2b  = (unsigned short*)(ws + 16 * MiB);  // later x4
    unsigned short* x3   = xb1;
    unsigned short* x4   = x2b;
    unsigned short* W2t  = (unsigned short*)(ws + 32 * MiB);
    unsigned short* W3t  = (unsigned short*)(ws + 34 * MiB);
    unsigned short* W41t = (unsigned short*)(ws + 36 * MiB);
    unsigned short* W42t = (unsigned short*)(ws + 36 * MiB + 512 * 1024);
    float*          b3c  = (float*)(ws + 37 * MiB);

    prep_weights<<<dim3(32, 32, 6), 256, 0, stream>>>(
        W2, W31, W32, W41, W42, b31, b32, W2t, W3t, W41t, W42t, b3c);

    layer1_kernel<<<8192, 256, 0, stream>>>(x, W1, b1, xb1);

    dim3 gL2(1024 / TN, 8192 / TM);
    gemm_bf16<<<gL2, 256, 0, stream>>>(xb1, 1024, W2t, 1024, b2, x2b, 1024, 1024);
    gemm_bf16<<<gL2, 256, 0, stream>>>(x2b, 1024, W3t, 1024, b3c, x3, 1024, 1024);

    gemm_bf16_l4<<<dim3(8, 64), 256, 0, stream>>>(x3, W41t, W42t, b41, b42, x4);

    head_kernel<<<2048, 256, 0, stream>>>(x4, W51, b51, W52, b52,
                                          x, mean, stdv, mean_label, std_label, out);
}

// Round 4
// 88.862 us; speedup vs baseline: 7.0081x; 1.1078x over previous
//
#include <hip/hip_runtime.h>
#include <hip/hip_bf16.h>
#include <math.h>

// ---------------------------------------------------------------------------
// BarrierNet forward, round 4.
// GEMM: BM=128 x BN=256 x BK=64, 512 threads (8 waves, wave-tile 64x64),
// double-buffered LDS (96 KiB), counted s_waitcnt vmcnt(6), and a
// conflict-free XOR-swizzled LDS layout realized by pre-swizzling the
// per-lane GLOBAL source of global_load_lds (linear LDS dest) and applying
// the same XOR on the ds_read side (rule: both-sides-or-neither).
//   granule (row, kq) [8 bf16]  ->  LDS granule row*8 + (kq ^ (row&7))
// Sync structure identical to round 3 (verified): reads -> lgkm0 -> bar ->
// stage(t+2 into just-freed buffer) -> MFMA -> vmcnt(6) -> bar.
// ---------------------------------------------------------------------------

typedef __attribute__((ext_vector_type(4))) float f32x4;
typedef __attribute__((ext_vector_type(8))) short bf16x8;

static __device__ __forceinline__ unsigned short f2bf(float f) {
    unsigned int u = __float_as_uint(f);
    unsigned int r = (u + 0x7fffu + ((u >> 16) & 1u)) >> 16;
    return (unsigned short)r;
}
static __device__ __forceinline__ float bf2f(unsigned short h) {
    return __uint_as_float(((unsigned int)h) << 16);
}

#define TBM 128
#define TBN 256
#define TBK 64

#define GLL(gp, lp) __builtin_amdgcn_global_load_lds( \
    (const __attribute__((address_space(1))) void*)(gp), \
    (__attribute__((address_space(3))) void*)(lp), 16, 0, 0)

#define LGKM0() asm volatile("s_waitcnt lgkmcnt(0)" ::: "memory")
#define VMC(N)  asm volatile("s_waitcnt vmcnt(" #N ")" ::: "memory")
#define BAR()   __builtin_amdgcn_s_barrier()
#define SB0()   __builtin_amdgcn_sched_barrier(0)

// C[., c0+j] = relu(A[m0+i,:] . Bt[n0b+j,:] + bias[n0b+j])
// A: bf16 row-major lda; Bt: bf16 row-major ldb (N x K); K % 128 == 0-ish:
// nt = K/64 must be even (K = 512 or 1024 here).
__device__ __forceinline__ void gemm_core(
    const unsigned short* __restrict__ A, int lda,
    const unsigned short* __restrict__ Bt, int ldb,
    const float* __restrict__ bias,
    unsigned short* __restrict__ C, int ldc,
    int K, int m0, int n0b, int c0)
{
    // A tile 128x64 (16 KiB), B tile 256x64 (32 KiB), x2 buffers = 96 KiB
    __shared__ __align__(16) short sA0[TBM * TBK], sA1[TBM * TBK];
    __shared__ __align__(16) short sB0v[TBN * TBK], sB1v[TBN * TBK];

    const int tid  = threadIdx.x;
    const int w    = tid >> 6;         // wave 0..7
    const int lane = tid & 63;

    // ---- staging addresses (pre-swizzled global source) ----
    // chunk = 1 KiB = 64 granules = 8 rows x 8 granules. lane l covers
    // LDS granule chunkbase + l -> logical row = base + (l>>3),
    //                              kq = (l&7) ^ ((l>>3)&7)
    const int srow = lane >> 3;                       // 0..7
    const int skq  = (lane & 7) ^ ((lane >> 3) & 7);  // 0..7
    // A chunks: wave w owns rows [16w, 16w+16) as 2 chunks
    const unsigned short* aP0 =
        A + (size_t)(m0 + 16 * w + srow) * lda + skq * 8;
    const unsigned short* aP1 = aP0 + 8 * lda;
    // B chunks: wave w owns rows [32w, 32w+32) as 4 chunks
    const unsigned short* bP0 =
        Bt + (size_t)(n0b + 32 * w + srow) * ldb + skq * 8;
    const unsigned short* bP1 = bP0 + 8 * ldb;
    const unsigned short* bP2 = bP0 + 16 * ldb;
    const unsigned short* bP3 = bP0 + 24 * ldb;

    // ---- fragment geometry (wave-tile 64x64; 2M x 4N wave grid) ----
    const int wrow = (w >> 2) * 64;    // 0 or 64
    const int wcol = (w & 3) * 64;     // 0,64,128,192
    const int fr = lane & 15;
    const int fq = lane >> 4;          // 0..3
    // swizzled k-offset (shorts) for k-half kh: ((kh*4+fq) ^ (fr&7)) * 8
    const int swz0 = ((fq)     ^ (fr & 7)) * 8;
    const int swz1 = ((4 + fq) ^ (fr & 7)) * 8;

    f32x4 acc[4][4] = {};
    const int nt = K / TBK;            // 16 or 8, even

    auto STAGE = [&](int kt, short* la, short* lb) {
        const size_t ko = (size_t)kt * TBK;
        GLL(aP0 + ko, la + (2 * w)     * 512);
        GLL(aP1 + ko, la + (2 * w + 1) * 512);
        GLL(bP0 + ko, lb + (4 * w)     * 512);
        GLL(bP1 + ko, lb + (4 * w + 1) * 512);
        GLL(bP2 + ko, lb + (4 * w + 2) * 512);
        GLL(bP3 + ko, lb + (4 * w + 3) * 512);
    };

    auto BODY = [&](int t, short* sAp, short* sBp) {
        bf16x8 af[2][4], bf[2][4];
        #pragma unroll
        for (int m = 0; m < 4; ++m) {
            const int r = (wrow + m * 16 + fr) * 64;
            af[0][m] = *reinterpret_cast<const bf16x8*>(&sAp[r + swz0]);
            af[1][m] = *reinterpret_cast<const bf16x8*>(&sAp[r + swz1]);
        }
        #pragma unroll
        for (int n = 0; n < 4; ++n) {
            const int r = (wcol + n * 16 + fr) * 64;
            bf[0][n] = *reinterpret_cast<const bf16x8*>(&sBp[r + swz0]);
            bf[1][n] = *reinterpret_cast<const bf16x8*>(&sBp[r + swz1]);
        }
        LGKM0();                       // my reads of this buffer done
        BAR();                         // everyone's reads done
        SB0();
        if (t + 2 < nt) STAGE(t + 2, sAp, sBp);   // overwrite freed buffer
        #pragma unroll
        for (int kh = 0; kh < 2; ++kh)
            #pragma unroll
            for (int m = 0; m < 4; ++m)
                #pragma unroll
                for (int n = 0; n < 4; ++n)
                    acc[m][n] = __builtin_amdgcn_mfma_f32_16x16x32_bf16(
                        af[kh][m], bf[kh][n], acc[m][n], 0, 0, 0);
        if (t + 1 < nt) {
            if (t + 2 < nt) { VMC(6); } else { VMC(0); }  // tile t+1 landed
            BAR();
            SB0();
        }
    };

    STAGE(0, sA0, sB0v);
    STAGE(1, sA1, sB1v);
    VMC(6);                            // tile 0 landed; tile 1 in flight
    BAR();
    SB0();

    for (int t = 0; t < nt; t += 2) {
        BODY(t,     sA0, sB0v);
        BODY(t + 1, sA1, sB1v);
    }

    // C/D layout: col = lane&15, row = (lane>>4)*4 + reg  [m89/m91 verified]
    #pragma unroll
    for (int n = 0; n < 4; ++n) {
        const int cl = wcol + n * 16 + fr;
        const float bv = bias[n0b + cl];
        #pragma unroll
        for (int m = 0; m < 4; ++m) {
            const int rbase = m0 + wrow + m * 16 + fq * 4;
            #pragma unroll
            for (int r = 0; r < 4; ++r) {
                float v = fmaxf(acc[m][n][r] + bv, 0.0f);
                C[(size_t)(rbase + r) * ldc + c0 + cl] = f2bf(v);
            }
        }
    }
}

__global__ __launch_bounds__(512, 2) void gemm_bf16(
    const unsigned short* __restrict__ A, int lda,
    const unsigned short* __restrict__ Bt, int ldb,
    const float* __restrict__ bias,
    unsigned short* __restrict__ C, int ldc, int K)
{
    const int n0 = blockIdx.x * TBN;
    const int m0 = blockIdx.y * TBM;
    gemm_core(A, lda, Bt, ldb, bias, C, ldc, K, m0, n0, n0);
}

// Grouped L4: blockIdx.x in 0..3 -> (g = x>>1, n-tile = x&1)
__global__ __launch_bounds__(512, 2) void gemm_bf16_l4(
    const unsigned short* __restrict__ x3,
    const unsigned short* __restrict__ W41t,
    const unsigned short* __restrict__ W42t,
    const float* __restrict__ b41, const float* __restrict__ b42,
    unsigned short* __restrict__ x4)
{
    const int g   = blockIdx.x >> 1;
    const int n0b = (blockIdx.x & 1) * TBN;
    const int m0  = blockIdx.y * TBM;
    const unsigned short* A  = x3 + (g ? 512 : 0);
    const unsigned short* Bt = g ? W42t : W41t;
    const float* bias        = g ? b42 : b41;
    gemm_core(A, 1024, Bt, 512, bias, x4, 1024, 512, m0, n0b, g * 512 + n0b);
}

// All weight prep in one kernel. z: 0=W2, 1=W31, 2=W32, 3=W41, 4=W42, 5=b3cat.
__global__ __launch_bounds__(256) void prep_weights(
    const float* __restrict__ W2,  const float* __restrict__ W31,
    const float* __restrict__ W32, const float* __restrict__ W41,
    const float* __restrict__ W42, const float* __restrict__ b31,
    const float* __restrict__ b32,
    unsigned short* __restrict__ W2t,  unsigned short* __restrict__ W3t,
    unsigned short* __restrict__ W41t, unsigned short* __restrict__ W42t,
    float* __restrict__ b3c)
{
    const int z = blockIdx.z;
    if (z == 5) {
        if (blockIdx.x == 0 && blockIdx.y == 0) {
            for (int i = threadIdx.x; i < 1024; i += 256)
                b3c[i] = (i < 512) ? b31[i] : b32[i - 512];
        }
        return;
    }
    const float* src; unsigned short* dst; int K, N;
    switch (z) {
        case 0:  src = W2;  dst = W2t;              K = 1024; N = 1024; break;
        case 1:  src = W31; dst = W3t;              K = 1024; N = 512;  break;
        case 2:  src = W32; dst = W3t + 512 * 1024; K = 1024; N = 512;  break;
        case 3:  src = W41; dst = W41t;             K = 512;  N = 512;  break;
        default: src = W42; dst = W42t;             K = 512;  N = 512;  break;
    }
    const int k0 = blockIdx.x * 32, n0 = blockIdx.y * 32;
    if (k0 >= K || n0 >= N) return;

    __shared__ float t[32][33];
    const int tx = threadIdx.x & 31, ty = threadIdx.x >> 5;  // 32 x 8
    #pragma unroll
    for (int i = 0; i < 32; i += 8)
        t[ty + i][tx] = src[(size_t)(k0 + ty + i) * N + n0 + tx];
    __syncthreads();
    #pragma unroll
    for (int i = 0; i < 32; i += 8)
        dst[(size_t)(n0 + ty + i) * K + k0 + tx] = f2bf(t[tx][ty + i]);
}

// Layer 1: K=5, N=1024, fp32 math, bf16 out.
__global__ __launch_bounds__(256) void layer1_kernel(
    const float* __restrict__ x, const float* __restrict__ W1,
    const float* __restrict__ b1, unsigned short* __restrict__ x1out)
{
    const int row = blockIdx.x;
    const int j4 = threadIdx.x * 4;
    float xr[5];
    #pragma unroll
    for (int k = 0; k < 5; ++k) xr[k] = x[row * 5 + k];
    float4 acc = *reinterpret_cast<const float4*>(&b1[j4]);
    #pragma unroll
    for (int k = 0; k < 5; ++k) {
        float4 wv = *reinterpret_cast<const float4*>(&W1[k * 1024 + j4]);
        acc.x = fmaf(xr[k], wv.x, acc.x);
        acc.y = fmaf(xr[k], wv.y, acc.y);
        acc.z = fmaf(xr[k], wv.z, acc.z);
        acc.w = fmaf(xr[k], wv.w, acc.w);
    }
    ushort4 o;
    o.x = f2bf(fmaxf(acc.x, 0.f));
    o.y = f2bf(fmaxf(acc.y, 0.f));
    o.z = f2bf(fmaxf(acc.z, 0.f));
    o.w = f2bf(fmaxf(acc.w, 0.f));
    *reinterpret_cast<ushort4*>(&x1out[(size_t)row * 1024 + j4]) = o;
}

// Heads + exact CBF/QP epilogue. One wave per batch row. x4 = [x41|x42], ld 1024.
__global__ __launch_bounds__(256) void head_kernel(
    const unsigned short* __restrict__ x4,
    const float* __restrict__ W51, const float* __restrict__ b51,
    const float* __restrict__ W52, const float* __restrict__ b52,
    const float* __restrict__ x,   const float* __restrict__ mean,
    const float* __restrict__ stdv, const float* __restrict__ mean_label,
    const float* __restrict__ std_label, float* __restrict__ out)
{
    const int wave = threadIdx.x >> 6;
    const int lane = threadIdx.x & 63;
    const int row = blockIdx.x * 4 + wave;

    const unsigned short* p41 = x4 + (size_t)row * 1024;
    const unsigned short* p42 = p41 + 512;

    float a0 = 0.f, a1 = 0.f, a2 = 0.f, a3 = 0.f;
    #pragma unroll
    for (int it = 0; it < 8; ++it) {
        const int k = lane + it * 64;
        const float v1 = bf2f(p41[k]);
        const float2 w5 = *reinterpret_cast<const float2*>(&W51[k * 2]);
        a0 = fmaf(v1, w5.x, a0);
        a1 = fmaf(v1, w5.y, a1);
        const float v2 = bf2f(p42[k]);
        const float2 w6 = *reinterpret_cast<const float2*>(&W52[k * 2]);
        a2 = fmaf(v2, w6.x, a2);
        a3 = fmaf(v2, w6.y, a3);
    }
    #pragma unroll
    for (int off = 32; off >= 1; off >>= 1) {
        a0 += __shfl_down(a0, off);
        a1 += __shfl_down(a1, off);
        a2 += __shfl_down(a2, off);
        a3 += __shfl_down(a3, off);
    }

    if (lane == 0) {
        const float L1c = 3.0f, L2c = 3.0f, OBSX = 0.0f, OBSY = 7.0f, Rc = 4.0f;
        const float t1 = x[row * 5 + 0] * stdv[0] + mean[0];
        const float w1 = x[row * 5 + 1] * stdv[1] + mean[1];
        const float t2 = x[row * 5 + 2] * stdv[2] + mean[2];
        const float w2 = x[row * 5 + 3] * stdv[3] + mean[3];
        const float s1 = sinf(t1), c1 = cosf(t1);
        const float s2 = sinf(t2), c2 = cosf(t2);
        const float px = L1c * c1 + L2c * c2 - OBSX;
        const float py = L1c * s1 + L2c * s2 - OBSY;
        const float vx = -L1c * s1 * w1 - L2c * s2 * w2;
        const float vy =  L1c * c1 * w1 + L2c * c2 * w2;
        const float barrier = px * px + py * py - Rc * Rc;
        const float b_dot = 2.0f * (px * vx + py * vy);
        const float Lf2b = 2.0f * (vx * vx + vy * vy)
                         + 2.0f * px * (-L1c * c1 * w1 * w1 - L2c * c2 * w2 * w2)
                         + 2.0f * py * (-L1c * s1 * w1 * w1 - L2c * s2 * w2 * w2);
        const float G1 = -(2.0f * px * (-L1c * s1) + 2.0f * py * (L1c * c1));
        const float G2 = -(2.0f * px * (-L2c * s2) + 2.0f * py * (L2c * c2));

        const float x51_0 = a0 + b51[0];
        const float x51_1 = a1 + b51[1];
        const float z0 = a2 + b52[0];
        const float z1 = a3 + b52[1];
        const float x52_0 = 4.0f / (1.0f + expf(-z0));
        const float x52_1 = 4.0f / (1.0f + expf(-z1));

        const float u0_0 = -x51_0;
        const float u0_1 = -x51_1;
        const float h = Lf2b + (x52_0 + x52_1) * b_dot + x52_0 * x52_1 * barrier;
        const float viol = G1 * u0_0 + G2 * u0_1 - h;
        const float lam = fmaxf(viol, 0.0f) / (G1 * G1 + G2 * G2 + 1e-12f);
        const float u_0 = u0_0 - lam * G1;
        const float u_1 = u0_1 - lam * G2;
        out[row * 2 + 0] = (u_0 - mean_label[0]) / std_label[0];
        out[row * 2 + 1] = (u_1 - mean_label[1]) / std_label[1];
    }
}

extern "C" void kernel_launch(void* const* d_in, const int* in_sizes, int n_in,
                              void* d_out, int out_size, void* d_ws, size_t ws_size,
                              hipStream_t stream) {
    const float* x          = (const float*)d_in[0];
    const float* mean       = (const float*)d_in[2];
    const float* stdv       = (const float*)d_in[3];
    const float* mean_label = (const float*)d_in[4];
    const float* std_label  = (const float*)d_in[5];
    const float* W1  = (const float*)d_in[6];   const float* b1  = (const float*)d_in[7];
    const float* W2  = (const float*)d_in[8];   const float* b2  = (const float*)d_in[9];
    const float* W31 = (const float*)d_in[10];  const float* b31 = (const float*)d_in[11];
    const float* W32 = (const float*)d_in[12];  const float* b32 = (const float*)d_in[13];
    const float* W41 = (const float*)d_in[14];  const float* b41 = (const float*)d_in[15];
    const float* W42 = (const float*)d_in[16];  const float* b42 = (const float*)d_in[17];
    const float* W51 = (const float*)d_in[18];  const float* b51 = (const float*)d_in[19];
    const float* W52 = (const float*)d_in[20];  const float* b52 = (const float*)d_in[21];
    float* out = (float*)d_out;

    char* ws = (char*)d_ws;
    const size_t MiB = 1024 * 1024;
    unsigned short* xb1  = (unsigned short*)(ws + 0);         // later x3
    unsigned short* x2b  = (unsigned short*)(ws + 16 * MiB);  // later x4
    unsigned short* x3   = xb1;
    unsigned short* x4   = x2b;
    unsigned short* W2t  = (unsigned short*)(ws + 32 * MiB);
    unsigned short* W3t  = (unsigned short*)(ws + 34 * MiB);
    unsigned short* W41t = (unsigned short*)(ws + 36 * MiB);
    unsigned short* W42t = (unsigned short*)(ws + 36 * MiB + 512 * 1024);
    float*          b3c  = (float*)(ws + 37 * MiB);

    prep_weights<<<dim3(32, 32, 6), 256, 0, stream>>>(
        W2, W31, W32, W41, W42, b31, b32, W2t, W3t, W41t, W42t, b3c);

    layer1_kernel<<<8192, 256, 0, stream>>>(x, W1, b1, xb1);

    dim3 gBig(1024 / TBN, 8192 / TBM);          // 4 x 64 = 256 blocks
    gemm_bf16<<<gBig, 512, 0, stream>>>(xb1, 1024, W2t, 1024, b2, x2b, 1024, 1024);
    gemm_bf16<<<gBig, 512, 0, stream>>>(x2b, 1024, W3t, 1024, b3c, x3, 1024, 1024);

    gemm_bf16_l4<<<dim3(4, 64), 512, 0, stream>>>(x3, W41t, W42t, b41, b42, x4);

    head_kernel<<<2048, 256, 0, stream>>>(x4, W51, b51, W52, b52,
                                          x, mean, stdv, mean_label, std_label, out);
}

// Round 5
// 78.814 us; speedup vs baseline: 7.9016x; 1.1275x over previous
//
#include <hip/hip_runtime.h>
#include <hip/hip_bf16.h>
#include <math.h>

// ---------------------------------------------------------------------------
// BarrierNet forward, round 5.
// GEMM: BM=128 x BN=256 x BK=64, 512 threads (8 waves, wave-tile 64x64),
// TRIPLE-buffered LDS (144 KiB), ONE barrier per K-tile, stage-ahead-2,
// counted s_waitcnt vmcnt(6) (never 0 mid-loop), s_setprio around MFMA.
// Data-waits happen per-wave AFTER the barrier (compiler-inserted lgkmcnt
// before each MFMA use) -> LDS pipe and MFMA pipe overlap across waves.
// Buffer-overwrite safety: STAGE(t+2 -> buf[(t+2)%3]); that buffer's readers
// (iter t-1) finished their reads before their own MFMAs (data dep), which
// precede the end-of-iter barrier, which precedes this STAGE issue. No race.
// Conflict-free XOR-swizzled LDS layout via pre-swizzled GLOBAL source of
// global_load_lds (linear LDS dest) + same XOR on ds_read side (verified R4).
// XCD swizzle: 256 blocks -> XCD k owns m-panels 8k..8k+7 (A+B fit 4MiB L2).
// ---------------------------------------------------------------------------

typedef __attribute__((ext_vector_type(4))) float f32x4;
typedef __attribute__((ext_vector_type(8))) short bf16x8;

static __device__ __forceinline__ unsigned short f2bf(float f) {
    unsigned int u = __float_as_uint(f);
    unsigned int r = (u + 0x7fffu + ((u >> 16) & 1u)) >> 16;
    return (unsigned short)r;
}
static __device__ __forceinline__ float bf2f(unsigned short h) {
    return __uint_as_float(((unsigned int)h) << 16);
}

#define TBM 128
#define TBN 256
#define TBK 64

#define GLL(gp, lp) __builtin_amdgcn_global_load_lds( \
    (const __attribute__((address_space(1))) void*)(gp), \
    (__attribute__((address_space(3))) void*)(lp), 16, 0, 0)

#define VMC(N)  asm volatile("s_waitcnt vmcnt(" #N ")" ::: "memory")
#define BAR()   __builtin_amdgcn_s_barrier()
#define SB0()   __builtin_amdgcn_sched_barrier(0)

// C[., c0+j] = relu(A[m0+i,:] . Bt[n0b+j,:] + bias[n0b+j])
// A: bf16 row-major lda; Bt: bf16 row-major ldb (N x K); nt = K/64 >= 3.
__device__ __forceinline__ void gemm_core(
    const unsigned short* __restrict__ A, int lda,
    const unsigned short* __restrict__ Bt, int ldb,
    const float* __restrict__ bias,
    unsigned short* __restrict__ C, int ldc,
    int K, int m0, int n0b, int c0)
{
    // A tile 16 KiB, B tile 32 KiB, x3 buffers = 144 KiB
    __shared__ __align__(16) short sA[3][TBM * TBK];
    __shared__ __align__(16) short sB[3][TBN * TBK];

    const int tid  = threadIdx.x;
    const int w    = tid >> 6;         // wave 0..7
    const int lane = tid & 63;

    // ---- staging addresses (pre-swizzled global source) ----
    // chunk = 1 KiB = 64 granules = 8 rows x 8 granules. lane l covers
    // LDS granule chunkbase + l -> logical row = base + (l>>3),
    //                              kq = (l&7) ^ ((l>>3)&7)
    const int srow = lane >> 3;                       // 0..7
    const int skq  = (lane & 7) ^ ((lane >> 3) & 7);  // 0..7
    const unsigned short* aP0 =
        A + (size_t)(m0 + 16 * w + srow) * lda + skq * 8;
    const unsigned short* aP1 = aP0 + 8 * lda;
    const unsigned short* bP0 =
        Bt + (size_t)(n0b + 32 * w + srow) * ldb + skq * 8;
    const unsigned short* bP1 = bP0 + 8 * ldb;
    const unsigned short* bP2 = bP0 + 16 * ldb;
    const unsigned short* bP3 = bP0 + 24 * ldb;

    // ---- fragment geometry (wave-tile 64x64; 2M x 4N wave grid) ----
    const int wrow = (w >> 2) * 64;
    const int wcol = (w & 3) * 64;
    const int fr = lane & 15;
    const int fq = lane >> 4;          // 0..3
    const int swz0 = ((fq)     ^ (fr & 7)) * 8;   // swizzled k-offsets (shorts)
    const int swz1 = ((4 + fq) ^ (fr & 7)) * 8;

    f32x4 acc[4][4] = {};
    const int nt = K / TBK;            // 16 or 8

    auto STAGE = [&](int kt, int b) {
        const size_t ko = (size_t)kt * TBK;
        short* la = &sA[b][0];
        short* lb = &sB[b][0];
        GLL(aP0 + ko, la + (2 * w)     * 512);
        GLL(aP1 + ko, la + (2 * w + 1) * 512);
        GLL(bP0 + ko, lb + (4 * w)     * 512);
        GLL(bP1 + ko, lb + (4 * w + 1) * 512);
        GLL(bP2 + ko, lb + (4 * w + 2) * 512);
        GLL(bP3 + ko, lb + (4 * w + 3) * 512);
    };

    STAGE(0, 0);
    STAGE(1, 1);
    VMC(6);                            // tile 0 landed; tile 1 in flight
    BAR();
    SB0();

    int cur = 0, stg = 2;              // stg = (t+2)%3
    for (int t = 0; t < nt; ++t) {
        const short* sAp = &sA[cur][0];
        const short* sBp = &sB[cur][0];

        bf16x8 af[2][4], bf[2][4];
        #pragma unroll
        for (int m = 0; m < 4; ++m) {
            const int r = (wrow + m * 16 + fr) * 64;
            af[0][m] = *reinterpret_cast<const bf16x8*>(&sAp[r + swz0]);
            af[1][m] = *reinterpret_cast<const bf16x8*>(&sAp[r + swz1]);
        }
        #pragma unroll
        for (int n = 0; n < 4; ++n) {
            const int r = (wcol + n * 16 + fr) * 64;
            bf[0][n] = *reinterpret_cast<const bf16x8*>(&sBp[r + swz0]);
            bf[1][n] = *reinterpret_cast<const bf16x8*>(&sBp[r + swz1]);
        }

        if (t + 2 < nt) STAGE(t + 2, stg);   // buffer freed at iter t-1

        __builtin_amdgcn_s_setprio(1);
        #pragma unroll
        for (int kh = 0; kh < 2; ++kh)
            #pragma unroll
            for (int m = 0; m < 4; ++m)
                #pragma unroll
                for (int n = 0; n < 4; ++n)
                    acc[m][n] = __builtin_amdgcn_mfma_f32_16x16x32_bf16(
                        af[kh][m], bf[kh][n], acc[m][n], 0, 0, 0);
        __builtin_amdgcn_s_setprio(0);

        if (t + 1 < nt) {
            if (t + 2 < nt) { VMC(6); } else { VMC(0); }  // tile t+1 landed
            BAR();
            SB0();
        }
        cur = (cur == 2) ? 0 : cur + 1;
        stg = (stg == 2) ? 0 : stg + 1;
    }

    // C/D layout: col = lane&15, row = (lane>>4)*4 + reg  [m89/m91 verified]
    #pragma unroll
    for (int n = 0; n < 4; ++n) {
        const int cl = wcol + n * 16 + fr;
        const float bv = bias[n0b + cl];
        #pragma unroll
        for (int m = 0; m < 4; ++m) {
            const int rbase = m0 + wrow + m * 16 + fq * 4;
            #pragma unroll
            for (int r = 0; r < 4; ++r) {
                float v = fmaxf(acc[m][n][r] + bv, 0.0f);
                C[(size_t)(rbase + r) * ldc + c0 + cl] = f2bf(v);
            }
        }
    }
}

// XCD-bijective swizzle for 256-block grids (4 x 64): XCD k (= bid%8) gets
// sids 32k..32k+31 -> m-panels 8k..8k+7, all 4 n-tiles of each.
static __device__ __forceinline__ int xcd_sid() {
    const int bid = blockIdx.y * gridDim.x + blockIdx.x;   // 0..255
    return (bid & 7) * 32 + (bid >> 3);
}

__global__ __launch_bounds__(512, 2) void gemm_bf16(
    const unsigned short* __restrict__ A, int lda,
    const unsigned short* __restrict__ Bt, int ldb,
    const float* __restrict__ bias,
    unsigned short* __restrict__ C, int ldc, int K)
{
    const int sid = xcd_sid();
    const int n0 = (sid & 3) * TBN;
    const int m0 = (sid >> 2) * TBM;
    gemm_core(A, lda, Bt, ldb, bias, C, ldc, K, m0, n0, n0);
}

// Grouped L4: x' = sid&3 -> (g = x'>>1, n-half = x'&1)
__global__ __launch_bounds__(512, 2) void gemm_bf16_l4(
    const unsigned short* __restrict__ x3,
    const unsigned short* __restrict__ W41t,
    const unsigned short* __restrict__ W42t,
    const float* __restrict__ b41, const float* __restrict__ b42,
    unsigned short* __restrict__ x4)
{
    const int sid = xcd_sid();
    const int xp  = sid & 3;
    const int g   = xp >> 1;
    const int n0b = (xp & 1) * TBN;
    const int m0  = (sid >> 2) * TBM;
    const unsigned short* A  = x3 + (g ? 512 : 0);
    const unsigned short* Bt = g ? W42t : W41t;
    const float* bias        = g ? b42 : b41;
    gemm_core(A, 1024, Bt, 512, bias, x4, 1024, 512, m0, n0b, g * 512 + n0b);
}

// All prep in one kernel.
// z: 0=W2, 1=W31, 2=W32, 3=W41, 4=W42, 5=b3cat, 6=layer1 (x@W1+b1,relu->bf16)
__global__ __launch_bounds__(256) void prep_weights(
    const float* __restrict__ W2,  const float* __restrict__ W31,
    const float* __restrict__ W32, const float* __restrict__ W41,
    const float* __restrict__ W42, const float* __restrict__ b31,
    const float* __restrict__ b32,
    const float* __restrict__ x,   const float* __restrict__ W1,
    const float* __restrict__ b1,
    unsigned short* __restrict__ W2t,  unsigned short* __restrict__ W3t,
    unsigned short* __restrict__ W41t, unsigned short* __restrict__ W42t,
    float* __restrict__ b3c, unsigned short* __restrict__ xb1)
{
    const int z = blockIdx.z;
    if (z == 6) {
        // layer1: 32x32=1024 blocks, each does 8 rows x 1024 cols.
        const int r0 = (blockIdx.y * 32 + blockIdx.x) * 8;
        const int j4 = threadIdx.x * 4;
        float4 wv[5];
        #pragma unroll
        for (int k = 0; k < 5; ++k)
            wv[k] = *reinterpret_cast<const float4*>(&W1[k * 1024 + j4]);
        const float4 bb = *reinterpret_cast<const float4*>(&b1[j4]);
        #pragma unroll
        for (int r = 0; r < 8; ++r) {
            const float* xr = &x[(size_t)(r0 + r) * 5];
            float4 acc = bb;
            #pragma unroll
            for (int k = 0; k < 5; ++k) {
                const float xv = xr[k];
                acc.x = fmaf(xv, wv[k].x, acc.x);
                acc.y = fmaf(xv, wv[k].y, acc.y);
                acc.z = fmaf(xv, wv[k].z, acc.z);
                acc.w = fmaf(xv, wv[k].w, acc.w);
            }
            ushort4 o;
            o.x = f2bf(fmaxf(acc.x, 0.f));
            o.y = f2bf(fmaxf(acc.y, 0.f));
            o.z = f2bf(fmaxf(acc.z, 0.f));
            o.w = f2bf(fmaxf(acc.w, 0.f));
            *reinterpret_cast<ushort4*>(&xb1[(size_t)(r0 + r) * 1024 + j4]) = o;
        }
        return;
    }
    if (z == 5) {
        if (blockIdx.x == 0 && blockIdx.y == 0) {
            for (int i = threadIdx.x; i < 1024; i += 256)
                b3c[i] = (i < 512) ? b31[i] : b32[i - 512];
        }
        return;
    }
    const float* src; unsigned short* dst; int K, N;
    switch (z) {
        case 0:  src = W2;  dst = W2t;              K = 1024; N = 1024; break;
        case 1:  src = W31; dst = W3t;              K = 1024; N = 512;  break;
        case 2:  src = W32; dst = W3t + 512 * 1024; K = 1024; N = 512;  break;
        case 3:  src = W41; dst = W41t;             K = 512;  N = 512;  break;
        default: src = W42; dst = W42t;             K = 512;  N = 512;  break;
    }
    const int k0 = blockIdx.x * 32, n0 = blockIdx.y * 32;
    if (k0 >= K || n0 >= N) return;

    __shared__ float t[32][33];
    const int tx = threadIdx.x & 31, ty = threadIdx.x >> 5;  // 32 x 8
    #pragma unroll
    for (int i = 0; i < 32; i += 8)
        t[ty + i][tx] = src[(size_t)(k0 + ty + i) * N + n0 + tx];
    __syncthreads();
    #pragma unroll
    for (int i = 0; i < 32; i += 8)
        dst[(size_t)(n0 + ty + i) * K + k0 + tx] = f2bf(t[tx][ty + i]);
}

// Heads + exact CBF/QP epilogue. One wave per batch row; vectorized loads.
// lane covers k = lane*8 .. lane*8+7 of each 512-dot.
__global__ __launch_bounds__(256) void head_kernel(
    const unsigned short* __restrict__ x4,
    const float* __restrict__ W51, const float* __restrict__ b51,
    const float* __restrict__ W52, const float* __restrict__ b52,
    const float* __restrict__ x,   const float* __restrict__ mean,
    const float* __restrict__ stdv, const float* __restrict__ mean_label,
    const float* __restrict__ std_label, float* __restrict__ out)
{
    const int wave = threadIdx.x >> 6;
    const int lane = threadIdx.x & 63;
    const int row = blockIdx.x * 4 + wave;

    const unsigned short* p41 = x4 + (size_t)row * 1024;
    const bf16x8 v1 = *reinterpret_cast<const bf16x8*>(p41 + lane * 8);
    const bf16x8 v2 = *reinterpret_cast<const bf16x8*>(p41 + 512 + lane * 8);
    // W5x[k*2 .. k*2+1] for k in [lane*8, lane*8+8) = 16 contiguous floats
    const float4 q0 = *reinterpret_cast<const float4*>(W51 + lane * 16 + 0);
    const float4 q1 = *reinterpret_cast<const float4*>(W51 + lane * 16 + 4);
    const float4 q2 = *reinterpret_cast<const float4*>(W51 + lane * 16 + 8);
    const float4 q3 = *reinterpret_cast<const float4*>(W51 + lane * 16 + 12);
    const float4 s0 = *reinterpret_cast<const float4*>(W52 + lane * 16 + 0);
    const float4 s1 = *reinterpret_cast<const float4*>(W52 + lane * 16 + 4);
    const float4 s2 = *reinterpret_cast<const float4*>(W52 + lane * 16 + 8);
    const float4 s3 = *reinterpret_cast<const float4*>(W52 + lane * 16 + 12);

    float a0, a1, a2, a3;
    {
        const float e0 = bf2f((unsigned short)v1[0]), e1 = bf2f((unsigned short)v1[1]),
                    e2 = bf2f((unsigned short)v1[2]), e3 = bf2f((unsigned short)v1[3]),
                    e4 = bf2f((unsigned short)v1[4]), e5 = bf2f((unsigned short)v1[5]),
                    e6 = bf2f((unsigned short)v1[6]), e7 = bf2f((unsigned short)v1[7]);
        a0 = e0*q0.x + e1*q0.z + e2*q1.x + e3*q1.z + e4*q2.x + e5*q2.z + e6*q3.x + e7*q3.z;
        a1 = e0*q0.y + e1*q0.w + e2*q1.y + e3*q1.w + e4*q2.y + e5*q2.w + e6*q3.y + e7*q3.w;
        const float f0 = bf2f((unsigned short)v2[0]), f1 = bf2f((unsigned short)v2[1]),
                    f2 = bf2f((unsigned short)v2[2]), f3 = bf2f((unsigned short)v2[3]),
                    f4 = bf2f((unsigned short)v2[4]), f5 = bf2f((unsigned short)v2[5]),
                    f6 = bf2f((unsigned short)v2[6]), f7 = bf2f((unsigned short)v2[7]);
        a2 = f0*s0.x + f1*s0.z + f2*s1.x + f3*s1.z + f4*s2.x + f5*s2.z + f6*s3.x + f7*s3.z;
        a3 = f0*s0.y + f1*s0.w + f2*s1.y + f3*s1.w + f4*s2.y + f5*s2.w + f6*s3.y + f7*s3.w;
    }
    #pragma unroll
    for (int off = 32; off >= 1; off >>= 1) {
        a0 += __shfl_down(a0, off);
        a1 += __shfl_down(a1, off);
        a2 += __shfl_down(a2, off);
        a3 += __shfl_down(a3, off);
    }

    if (lane == 0) {
        const float L1c = 3.0f, L2c = 3.0f, OBSX = 0.0f, OBSY = 7.0f, Rc = 4.0f;
        const float t1 = x[row * 5 + 0] * stdv[0] + mean[0];
        const float w1 = x[row * 5 + 1] * stdv[1] + mean[1];
        const float t2 = x[row * 5 + 2] * stdv[2] + mean[2];
        const float w2 = x[row * 5 + 3] * stdv[3] + mean[3];
        const float s1v = sinf(t1), c1 = cosf(t1);
        const float s2v = sinf(t2), c2 = cosf(t2);
        const float px = L1c * c1 + L2c * c2 - OBSX;
        const float py = L1c * s1v + L2c * s2v - OBSY;
        const float vx = -L1c * s1v * w1 - L2c * s2v * w2;
        const float vy =  L1c * c1 * w1 + L2c * c2 * w2;
        const float barrier = px * px + py * py - Rc * Rc;
        const float b_dot = 2.0f * (px * vx + py * vy);
        const float Lf2b = 2.0f * (vx * vx + vy * vy)
                         + 2.0f * px * (-L1c * c1 * w1 * w1 - L2c * c2 * w2 * w2)
                         + 2.0f * py * (-L1c * s1v * w1 * w1 - L2c * s2v * w2 * w2);
        const float G1 = -(2.0f * px * (-L1c * s1v) + 2.0f * py * (L1c * c1));
        const float G2 = -(2.0f * px * (-L2c * s2v) + 2.0f * py * (L2c * c2));

        const float x51_0 = a0 + b51[0];
        const float x51_1 = a1 + b51[1];
        const float z0 = a2 + b52[0];
        const float z1 = a3 + b52[1];
        const float x52_0 = 4.0f / (1.0f + expf(-z0));
        const float x52_1 = 4.0f / (1.0f + expf(-z1));

        const float u0_0 = -x51_0;
        const float u0_1 = -x51_1;
        const float h = Lf2b + (x52_0 + x52_1) * b_dot + x52_0 * x52_1 * barrier;
        const float viol = G1 * u0_0 + G2 * u0_1 - h;
        const float lam = fmaxf(viol, 0.0f) / (G1 * G1 + G2 * G2 + 1e-12f);
        const float u_0 = u0_0 - lam * G1;
        const float u_1 = u0_1 - lam * G2;
        out[row * 2 + 0] = (u_0 - mean_label[0]) / std_label[0];
        out[row * 2 + 1] = (u_1 - mean_label[1]) / std_label[1];
    }
}

extern "C" void kernel_launch(void* const* d_in, const int* in_sizes, int n_in,
                              void* d_out, int out_size, void* d_ws, size_t ws_size,
                              hipStream_t stream) {
    const float* x          = (const float*)d_in[0];
    const float* mean       = (const float*)d_in[2];
    const float* stdv       = (const float*)d_in[3];
    const float* mean_label = (const float*)d_in[4];
    const float* std_label  = (const float*)d_in[5];
    const float* W1  = (const float*)d_in[6];   const float* b1  = (const float*)d_in[7];
    const float* W2  = (const float*)d_in[8];   const float* b2  = (const float*)d_in[9];
    const float* W31 = (const float*)d_in[10];  const float* b31 = (const float*)d_in[11];
    const float* W32 = (const float*)d_in[12];  const float* b32 = (const float*)d_in[13];
    const float* W41 = (const float*)d_in[14];  const float* b41 = (const float*)d_in[15];
    const float* W42 = (const float*)d_in[16];  const float* b42 = (const float*)d_in[17];
    const float* W51 = (const float*)d_in[18];  const float* b51 = (const float*)d_in[19];
    const float* W52 = (const float*)d_in[20];  const float* b52 = (const float*)d_in[21];
    float* out = (float*)d_out;

    char* ws = (char*)d_ws;
    const size_t MiB = 1024 * 1024;
    unsigned short* xb1  = (unsigned short*)(ws + 0);         // later x3
    unsigned short* x2b  = (unsigned short*)(ws + 16 * MiB);  // later x4
    unsigned short* x3   = xb1;
    unsigned short* x4   = x2b;
    unsigned short* W2t  = (unsigned short*)(ws + 32 * MiB);
    unsigned short* W3t  = (unsigned short*)(ws + 34 * MiB);
    unsigned short* W41t = (unsigned short*)(ws + 36 * MiB);
    unsigned short* W42t = (unsigned short*)(ws + 36 * MiB + 512 * 1024);
    float*          b3c  = (float*)(ws + 37 * MiB);

    prep_weights<<<dim3(32, 32, 7), 256, 0, stream>>>(
        W2, W31, W32, W41, W42, b31, b32, x, W1, b1,
        W2t, W3t, W41t, W42t, b3c, xb1);

    dim3 gBig(1024 / TBN, 8192 / TBM);          // 4 x 64 = 256 blocks
    gemm_bf16<<<gBig, 512, 0, stream>>>(xb1, 1024, W2t, 1024, b2, x2b, 1024, 1024);
    gemm_bf16<<<gBig, 512, 0, stream>>>(x2b, 1024, W3t, 1024, b3c, x3, 1024, 1024);

    gemm_bf16_l4<<<dim3(4, 64), 512, 0, stream>>>(x3, W41t, W42t, b41, b42, x4);

    head_kernel<<<2048, 256, 0, stream>>>(x4, W51, b51, W52, b52,
                                          x, mean, stdv, mean_label, std_label, out);
}